// Round 7
// baseline (202.500 us; speedup 1.0000x reference)
//
#include <hip/hip_runtime.h>

#define LDIM 64
#define CDIM 128
#define MAXPER 512
#define LOG128 4.8520302639196171f

typedef __attribute__((ext_vector_type(8))) short bfrag;   // 8 x bf16
typedef __attribute__((ext_vector_type(4))) float f32x4;

static __device__ __forceinline__ unsigned short f2bf(float f) {
    unsigned int x = __float_as_uint(f);
    unsigned int r = (x + 0x7fffu + ((x >> 16) & 1u)) >> 16;
    return (unsigned short)r;
}
static __device__ __forceinline__ float bf2f(unsigned int u) {
    return __uint_as_float(u << 16);
}

// ---- zero bucket counters + out ----
__global__ __launch_bounds__(256) void zero_kernel(uint4* __restrict__ p, size_t n16,
                                                   float* __restrict__ out, int out_size) {
    size_t i = (size_t)blockIdx.x * blockDim.x + threadIdx.x;
    size_t stride = (size_t)gridDim.x * blockDim.x;
    for (; i < n16; i += stride) p[i] = make_uint4(0u, 0u, 0u, 0u);
    if (blockIdx.x == 0 && threadIdx.x < (unsigned)out_size) out[threadIdx.x] = 0.f;
}

// ---- prep: bf16 tables + gene-bucket placement for cuts AND counts ----
__global__ __launch_bounds__(256) void prep1_kernel(
    const float* __restrict__ heights, unsigned short* __restrict__ hbf, int nheights,
    const float* __restrict__ latent, unsigned short* __restrict__ latbf, int nlat,
    const int* __restrict__ cut_pair, const int* __restrict__ cut_gene,
    const float* __restrict__ coord, const int* __restrict__ genes_oi,
    const int* __restrict__ local_cxg, unsigned int* __restrict__ bucket_cnt,
    unsigned int* __restrict__ bucket, unsigned int* __restrict__ cnt2,
    unsigned char* __restrict__ bucket2,
    int ncuts, int B, int G, int N, unsigned int magicG) {
    int stride = gridDim.x * blockDim.x;
    for (int i = blockIdx.x * blockDim.x + threadIdx.x; i < N; i += stride) {
        if (i < nheights) hbf[i] = f2bf(heights[i]);
        if (i < nlat) latbf[i] = f2bf(latent[i]);
        if (i < ncuts) {
            unsigned int p = (unsigned int)cut_pair[i];
            unsigned int cell = __umulhi(p, magicG);
            unsigned int g = p - cell * (unsigned int)G;
            unsigned int gg = (unsigned int)genes_oi[cut_gene[i]];
            int bin = (int)(coord[i] * 128.0f);
            bin = min(max(bin, 0), 127);
            unsigned int slot = atomicAdd(&bucket_cnt[g], 1u);
            if (slot < MAXPER)
                bucket[g * MAXPER + slot] = (cell << 24) | (gg << 7) | (unsigned int)bin;
            unsigned int q = (unsigned int)local_cxg[i];
            unsigned int cell2 = __umulhi(q, magicG);
            unsigned int g2 = q - cell2 * (unsigned int)G;
            unsigned int slot2 = atomicAdd(&cnt2[g2], 1u);
            if (slot2 < MAXPER)
                bucket2[g2 * MAXPER + slot2] = (unsigned char)cell2;
        }
    }
}

// ---- fused per-gene: MFMA delta (LDS) + mixture cuts + poisson ----
__global__ __launch_bounds__(512, 2) void fused_kernel(
    const float* __restrict__ latent, const unsigned short* __restrict__ latbf,
    const int* __restrict__ genes_oi, const float* __restrict__ logit_weight,
    const unsigned short* __restrict__ hbf, const unsigned int* __restrict__ bucket,
    const unsigned int* __restrict__ bucket_cnt,
    const unsigned int* __restrict__ cnt2, const unsigned char* __restrict__ bucket2,
    const int* __restrict__ cells_oi,
    const float* __restrict__ rho_weight, const float* __restrict__ rho_bias,
    const int* __restrict__ libsize, int B, int G, float* __restrict__ out) {
    __shared__ unsigned short dlds[256 * CDIM];   // 64 KB delta tile, row-swizzled
    __shared__ unsigned short blds[CDIM * LDIM];  // 16 KB B^T tile; reused: lcnt+red
    int t = threadIdx.x;
    int g = blockIdx.x;
    int gene = genes_oi[g];

    // ---- stage lw[gene] (f32 [k][n]) -> blds [n][k] bf16, XOR-swizzled ----
    {
        int n = t & 127;
        int k0 = (t >> 7) * 16;
        const float* src = logit_weight + (size_t)gene * LDIM * CDIM;
        float v[16];
        #pragma unroll
        for (int j = 0; j < 16; ++j) v[j] = src[(size_t)(k0 + j) * CDIM + n];
        #pragma unroll
        for (int h = 0; h < 2; ++h) {
            union { unsigned short u[8]; uint4 q; } pk;
            #pragma unroll
            for (int j = 0; j < 8; ++j) pk.u[j] = f2bf(v[h * 8 + j]);
            int kk = k0 + h * 8;
            *(uint4*)(blds + n * LDIM + (kk ^ ((n & 7) * 8))) = pk.q;
        }
    }
    __syncthreads();

    // ---- MFMA: wave w -> cells [32w, 32w+32) x 128 cols ----
    int wv = t >> 6, ln = t & 63;
    int l15 = ln & 15, l4 = ln >> 4;
    f32x4 acc[2][8];
    #pragma unroll
    for (int m = 0; m < 2; ++m)
        #pragma unroll
        for (int n = 0; n < 8; ++n) acc[m][n] = (f32x4){0.f, 0.f, 0.f, 0.f};

    #pragma unroll
    for (int ks = 0; ks < 2; ++ks) {
        int kk = ks * 32 + l4 * 8;
        bfrag a0 = *(const bfrag*)(latbf + (wv * 32 + l15) * LDIM + kk);
        bfrag a1 = *(const bfrag*)(latbf + (wv * 32 + 16 + l15) * LDIM + kk);
        #pragma unroll
        for (int n = 0; n < 8; ++n) {
            int col = n * 16 + l15;
            bfrag b = *(const bfrag*)(blds + col * LDIM + (kk ^ ((col & 7) * 8)));
            acc[0][n] = __builtin_amdgcn_mfma_f32_16x16x32_bf16(a0, b, acc[0][n], 0, 0, 0);
            acc[1][n] = __builtin_amdgcn_mfma_f32_16x16x32_bf16(a1, b, acc[1][n], 0, 0, 0);
        }
    }
    // D -> dlds (row-swizzled): row = wv*32 + m*16 + l4*4 + r, col = n*16 + l15
    #pragma unroll
    for (int m = 0; m < 2; ++m)
        #pragma unroll
        for (int n = 0; n < 8; ++n)
            #pragma unroll
            for (int r = 0; r < 4; ++r) {
                int row = wv * 32 + m * 16 + l4 * 4 + r;
                int col = n * 16 + l15;
                dlds[row * CDIM + (col ^ ((row & 7) * 8))] = f2bf(acc[m][n][r]);
            }
    __syncthreads();   // blds reads done; dlds visible

    // lcnt (256 u32) + red (8 f32) live in dead blds space
    unsigned int* lcnt = (unsigned int*)blds;
    float* red = (float*)(blds + 2048);
    if (t < 256) lcnt[t] = 0u;
    __syncthreads();

    // ---- per-gene count histogram into LDS ----
    {
        unsigned int c2 = cnt2[g];
        if (c2 > MAXPER) c2 = MAXPER;
        const unsigned char* b2 = bucket2 + (size_t)g * MAXPER;
        for (unsigned int i = (unsigned int)t; i < c2; i += 512u)
            atomicAdd(&lcnt[b2[i]], 1u);
    }

    // ---- mixture cuts for this gene's bucket: 16-lane group per cut ----
    float accs = 0.f;
    {
        unsigned int cnt = bucket_cnt[g];
        if (cnt > MAXPER) cnt = MAXPER;
        const unsigned int* bk = bucket + (size_t)g * MAXPER;
        int grp = t >> 4, sub = t & 15;
        for (unsigned int i = (unsigned int)grp; i < cnt; i += 32u) {
            unsigned int r = bk[i];
            int row = (int)(r >> 24);
            unsigned int gg = (r >> 7) & 0x1FFFu;
            uint4 dv = *(const uint4*)(dlds + row * CDIM + ((sub * 8) ^ ((row & 7) * 8)));
            uint4 hv = *(const uint4*)(hbf + ((size_t)gg << 7) + sub * 8);
            float h0 = bf2f(hv.x & 0xffffu) + bf2f(dv.x & 0xffffu);
            float h1 = bf2f(hv.x >> 16)     + bf2f(dv.x >> 16);
            float h2 = bf2f(hv.y & 0xffffu) + bf2f(dv.y & 0xffffu);
            float h3 = bf2f(hv.y >> 16)     + bf2f(dv.y >> 16);
            float h4 = bf2f(hv.z & 0xffffu) + bf2f(dv.z & 0xffffu);
            float h5 = bf2f(hv.z >> 16)     + bf2f(dv.z >> 16);
            float h6 = bf2f(hv.w & 0xffffu) + bf2f(dv.w & 0xffffu);
            float h7 = bf2f(hv.w >> 16)     + bf2f(dv.w >> 16);
            float m = fmaxf(fmaxf(fmaxf(h0, h1), fmaxf(h2, h3)),
                            fmaxf(fmaxf(h4, h5), fmaxf(h6, h7)));
            #pragma unroll
            for (int o = 1; o < 16; o <<= 1) m = fmaxf(m, __shfl_xor(m, o));
            float s = __expf(h0 - m) + __expf(h1 - m) + __expf(h2 - m) + __expf(h3 - m)
                    + __expf(h4 - m) + __expf(h5 - m) + __expf(h6 - m) + __expf(h7 - m);
            #pragma unroll
            for (int o = 1; o < 16; o <<= 1) s += __shfl_xor(s, o);
            int bin = (int)(r & 127u);
            int e = bin & 7;
            float sel = h0;
            sel = (e == 1) ? h1 : sel;
            sel = (e == 2) ? h2 : sel;
            sel = (e == 3) ? h3 : sel;
            sel = (e == 4) ? h4 : sel;
            sel = (e == 5) ? h5 : sel;
            sel = (e == 6) ? h6 : sel;
            sel = (e == 7) ? h7 : sel;
            float hsel = __shfl(sel, (ln & 48) | (bin >> 3));
            if (sub == 0) accs += hsel - (m + __logf(s)) + LOG128;
        }
    }
    __syncthreads();   // lcnt histogram complete

    // ---- poisson for this gene: thread t < B handles cell t ----
    if (t < B) {
        const float4* la = (const float4*)(latent + (size_t)t * LDIM);
        const float4* rw = (const float4*)(rho_weight + (size_t)gene * LDIM);
        float d = 0.f;
        #pragma unroll
        for (int k = 0; k < LDIM / 4; ++k) {
            float4 a = la[k], w = rw[k];
            d += a.x * w.x + a.y * w.y + a.z * w.z + a.w * w.w;
        }
        float rb = rho_bias[gene];
        float lib = (float)libsize[cells_oi[t]];
        float lrate = __logf(rb) + d + __logf(lib);
        float rate = __expf(lrate);
        unsigned int c = lcnt[t];
        float lgam = 0.f;
        for (unsigned int k = 2; k <= c; ++k) lgam += __logf((float)k);
        accs += (float)c * lrate - rate - lgam;
    }

    // ---- block reduce -> single atomic ----
    #pragma unroll
    for (int o = 32; o; o >>= 1) accs += __shfl_xor(accs, o);
    __syncthreads();
    if (ln == 0) red[wv] = accs;
    __syncthreads();
    if (t == 0) {
        float s = red[0] + red[1] + red[2] + red[3] + red[4] + red[5] + red[6] + red[7];
        atomicAdd(out, -s);
    }
}

extern "C" void kernel_launch(void* const* d_in, const int* in_sizes, int n_in,
                              void* d_out, int out_size, void* d_ws, size_t ws_size,
                              hipStream_t stream) {
    const float* latent         = (const float*)d_in[0];
    const int*   genes_oi       = (const int*)d_in[1];
    const int*   cells_oi       = (const int*)d_in[2];
    const float* cut_coord      = (const float*)d_in[3];
    const int*   cut_pair       = (const int*)d_in[4];
    const int*   cut_gene       = (const int*)d_in[5];
    const int*   local_cxg      = (const int*)d_in[6];
    const float* logit_weight   = (const float*)d_in[7];
    const float* rho_weight     = (const float*)d_in[8];
    const float* rho_bias       = (const float*)d_in[9];
    const int*   libsize        = (const int*)d_in[10];
    const float* spline_heights = (const float*)d_in[11];
    int G = in_sizes[1];
    int B = in_sizes[2];
    int ncuts = in_sizes[4];
    int nheights = in_sizes[11];
    int nlat = B * LDIM;
    unsigned int magicG = (unsigned int)((0x100000000ULL + (unsigned)G - 1) / (unsigned)G);

    // workspace layout (256-B aligned); zeroed prefix = bucket_cnt + cnt2
    char* ws = (char*)d_ws;
    size_t off = 0;
    unsigned int* bucket_cnt = (unsigned int*)(ws + off);
    off += ((size_t)G * 4 + 255) & ~(size_t)255;
    unsigned int* cnt2 = (unsigned int*)(ws + off);
    off += ((size_t)G * 4 + 255) & ~(size_t)255;
    size_t zero_bytes = off;
    unsigned int* bucket = (unsigned int*)(ws + off);
    off += ((size_t)G * MAXPER * 4 + 255) & ~(size_t)255;
    unsigned char* bucket2 = (unsigned char*)(ws + off);
    off += ((size_t)G * MAXPER + 255) & ~(size_t)255;
    unsigned short* hbf = (unsigned short*)(ws + off);
    off += ((size_t)nheights * 2 + 255) & ~(size_t)255;
    unsigned short* latbf = (unsigned short*)(ws + off);
    off += ((size_t)nlat * 2 + 255) & ~(size_t)255;

    float* out = (float*)d_out;
    zero_kernel<<<16, 256, 0, stream>>>((uint4*)ws, zero_bytes / 16, out, out_size);

    int N = ncuts > nheights ? ncuts : nheights;
    prep1_kernel<<<2048, 256, 0, stream>>>(
        spline_heights, hbf, nheights, latent, latbf, nlat,
        cut_pair, cut_gene, cut_coord, genes_oi, local_cxg,
        bucket_cnt, bucket, cnt2, bucket2, ncuts, B, G, N, magicG);
    fused_kernel<<<G, 512, 0, stream>>>(
        latent, latbf, genes_oi, logit_weight, hbf, bucket,
        bucket_cnt, cnt2, bucket2, cells_oi,
        rho_weight, rho_bias, libsize, B, G, out);
}

// Round 8
// 135.212 us; speedup vs baseline: 1.4976x; 1.4976x over previous
//
#include <hip/hip_runtime.h>

#define LDIM 64
#define CDIM 128
#define NREP 8
#define SUBCAP 64
#define MAXPER (NREP * SUBCAP)   // 512
#define LOG128 4.8520302639196171f

typedef __attribute__((ext_vector_type(8))) short bfrag;   // 8 x bf16
typedef __attribute__((ext_vector_type(4))) float f32x4;

static __device__ __forceinline__ unsigned short f2bf(float f) {
    unsigned int x = __float_as_uint(f);
    unsigned int r = (x + 0x7fffu + ((x >> 16) & 1u)) >> 16;
    return (unsigned short)r;
}
static __device__ __forceinline__ float bf2f(unsigned int u) {
    return __uint_as_float(u << 16);
}

// ---- zero countsT + replicated bucket counters + out ----
__global__ __launch_bounds__(256) void zero_kernel(uint4* __restrict__ p, size_t n16,
                                                   float* __restrict__ out, int out_size) {
    size_t i = (size_t)blockIdx.x * blockDim.x + threadIdx.x;
    size_t stride = (size_t)gridDim.x * blockDim.x;
    for (; i < n16; i += stride) p[i] = make_uint4(0u, 0u, 0u, 0u);
    if (blockIdx.x == 0 && threadIdx.x < (unsigned)out_size) out[threadIdx.x] = 0.f;
}

// ---- prep: bf16 tables + XCD-replicated gene-bucket append + counts histogram ----
__global__ __launch_bounds__(256) void prep1_kernel(
    const float* __restrict__ heights, unsigned short* __restrict__ hbf, int nheights,
    const float* __restrict__ latent, unsigned short* __restrict__ latbf, int nlat,
    const int* __restrict__ cut_pair, const int* __restrict__ cut_gene,
    const float* __restrict__ coord, const int* __restrict__ genes_oi,
    const int* __restrict__ local_cxg, unsigned int* __restrict__ cnt_rep,
    unsigned int* __restrict__ bucket, unsigned int* __restrict__ countsT,
    int ncuts, int B, int G, int N, unsigned int magicG) {
    int stride = gridDim.x * blockDim.x;
    int rep = blockIdx.x & (NREP - 1);   // ~= XCD id (round-robin dispatch)
    for (int i = blockIdx.x * blockDim.x + threadIdx.x; i < N; i += stride) {
        if (i < nheights) hbf[i] = f2bf(heights[i]);
        if (i < nlat) latbf[i] = f2bf(latent[i]);
        if (i < ncuts) {
            unsigned int p = (unsigned int)cut_pair[i];
            unsigned int cell = __umulhi(p, magicG);
            unsigned int g = p - cell * (unsigned int)G;
            unsigned int gg = (unsigned int)genes_oi[cut_gene[i]];
            int bin = (int)(coord[i] * 128.0f);
            bin = min(max(bin, 0), 127);
            unsigned int slot = atomicAdd(&cnt_rep[rep * G + (int)g], 1u);
            if (slot < SUBCAP)
                bucket[g * MAXPER + rep * SUBCAP + slot] =
                    (cell << 24) | (gg << 7) | (unsigned int)bin;
            unsigned int q = (unsigned int)local_cxg[i];
            unsigned int cell2 = __umulhi(q, magicG);
            unsigned int g2 = q - cell2 * (unsigned int)G;
            atomicAdd(&countsT[(size_t)g2 * (unsigned int)B + cell2], 1u);  // no return: cheap
        }
    }
}

// ---- fused per-gene: MFMA delta (LDS) + mixture cuts + poisson ----
__global__ __launch_bounds__(512, 2) void fused_kernel(
    const float* __restrict__ latent, const unsigned short* __restrict__ latbf,
    const int* __restrict__ genes_oi, const float* __restrict__ logit_weight,
    const unsigned short* __restrict__ hbf, const unsigned int* __restrict__ bucket,
    const unsigned int* __restrict__ cnt_rep, const unsigned int* __restrict__ countsT,
    const int* __restrict__ cells_oi,
    const float* __restrict__ rho_weight, const float* __restrict__ rho_bias,
    const int* __restrict__ libsize, int B, int G, float* __restrict__ out) {
    __shared__ unsigned short dlds[256 * CDIM];   // 64 KB delta tile, row-swizzled
    __shared__ unsigned short blds[CDIM * LDIM];  // 16 KB B^T tile; reused: red
    int t = threadIdx.x;
    int g = blockIdx.x;
    int gene = genes_oi[g];

    // ---- stage lw[gene] (f32 [k][n]) -> blds [n][k] bf16, XOR-swizzled ----
    {
        int n = t & 127;
        int k0 = (t >> 7) * 16;
        const float* src = logit_weight + (size_t)gene * LDIM * CDIM;
        float v[16];
        #pragma unroll
        for (int j = 0; j < 16; ++j) v[j] = src[(size_t)(k0 + j) * CDIM + n];
        #pragma unroll
        for (int h = 0; h < 2; ++h) {
            union { unsigned short u[8]; uint4 q; } pk;
            #pragma unroll
            for (int j = 0; j < 8; ++j) pk.u[j] = f2bf(v[h * 8 + j]);
            int kk = k0 + h * 8;
            *(uint4*)(blds + n * LDIM + (kk ^ ((n & 7) * 8))) = pk.q;
        }
    }
    __syncthreads();

    // ---- MFMA: wave w -> cells [32w, 32w+32) x 128 cols ----
    int wv = t >> 6, ln = t & 63;
    int l15 = ln & 15, l4 = ln >> 4;
    f32x4 acc[2][8];
    #pragma unroll
    for (int m = 0; m < 2; ++m)
        #pragma unroll
        for (int n = 0; n < 8; ++n) acc[m][n] = (f32x4){0.f, 0.f, 0.f, 0.f};

    #pragma unroll
    for (int ks = 0; ks < 2; ++ks) {
        int kk = ks * 32 + l4 * 8;
        bfrag a0 = *(const bfrag*)(latbf + (wv * 32 + l15) * LDIM + kk);
        bfrag a1 = *(const bfrag*)(latbf + (wv * 32 + 16 + l15) * LDIM + kk);
        #pragma unroll
        for (int n = 0; n < 8; ++n) {
            int col = n * 16 + l15;
            bfrag b = *(const bfrag*)(blds + col * LDIM + (kk ^ ((col & 7) * 8)));
            acc[0][n] = __builtin_amdgcn_mfma_f32_16x16x32_bf16(a0, b, acc[0][n], 0, 0, 0);
            acc[1][n] = __builtin_amdgcn_mfma_f32_16x16x32_bf16(a1, b, acc[1][n], 0, 0, 0);
        }
    }
    // D -> dlds (row-swizzled): row = wv*32 + m*16 + l4*4 + r, col = n*16 + l15
    #pragma unroll
    for (int m = 0; m < 2; ++m)
        #pragma unroll
        for (int n = 0; n < 8; ++n)
            #pragma unroll
            for (int r = 0; r < 4; ++r) {
                int row = wv * 32 + m * 16 + l4 * 4 + r;
                int col = n * 16 + l15;
                dlds[row * CDIM + (col ^ ((row & 7) * 8))] = f2bf(acc[m][n][r]);
            }
    __syncthreads();

    // ---- mixture cuts: 8 replica sub-lists, 16-lane group per cut ----
    float accs = 0.f;
    {
        const unsigned int* bk = bucket + (size_t)g * MAXPER;
        int grp = t >> 4, sub = t & 15;
        #pragma unroll
        for (int r = 0; r < NREP; ++r) {
            unsigned int cr = cnt_rep[r * G + g];
            if (cr > SUBCAP) cr = SUBCAP;
            const unsigned int* bs = bk + r * SUBCAP;
            for (unsigned int i = (unsigned int)grp; i < cr; i += 32u) {
                unsigned int rc = bs[i];
                int row = (int)(rc >> 24);
                unsigned int gg = (rc >> 7) & 0x1FFFu;
                uint4 dv = *(const uint4*)(dlds + row * CDIM + ((sub * 8) ^ ((row & 7) * 8)));
                uint4 hv = *(const uint4*)(hbf + ((size_t)gg << 7) + sub * 8);
                float h0 = bf2f(hv.x & 0xffffu) + bf2f(dv.x & 0xffffu);
                float h1 = bf2f(hv.x >> 16)     + bf2f(dv.x >> 16);
                float h2 = bf2f(hv.y & 0xffffu) + bf2f(dv.y & 0xffffu);
                float h3 = bf2f(hv.y >> 16)     + bf2f(dv.y >> 16);
                float h4 = bf2f(hv.z & 0xffffu) + bf2f(dv.z & 0xffffu);
                float h5 = bf2f(hv.z >> 16)     + bf2f(dv.z >> 16);
                float h6 = bf2f(hv.w & 0xffffu) + bf2f(dv.w & 0xffffu);
                float h7 = bf2f(hv.w >> 16)     + bf2f(dv.w >> 16);
                float m = fmaxf(fmaxf(fmaxf(h0, h1), fmaxf(h2, h3)),
                                fmaxf(fmaxf(h4, h5), fmaxf(h6, h7)));
                #pragma unroll
                for (int o = 1; o < 16; o <<= 1) m = fmaxf(m, __shfl_xor(m, o));
                float s = __expf(h0 - m) + __expf(h1 - m) + __expf(h2 - m) + __expf(h3 - m)
                        + __expf(h4 - m) + __expf(h5 - m) + __expf(h6 - m) + __expf(h7 - m);
                #pragma unroll
                for (int o = 1; o < 16; o <<= 1) s += __shfl_xor(s, o);
                int bin = (int)(rc & 127u);
                int e = bin & 7;
                float sel = h0;
                sel = (e == 1) ? h1 : sel;
                sel = (e == 2) ? h2 : sel;
                sel = (e == 3) ? h3 : sel;
                sel = (e == 4) ? h4 : sel;
                sel = (e == 5) ? h5 : sel;
                sel = (e == 6) ? h6 : sel;
                sel = (e == 7) ? h7 : sel;
                float hsel = __shfl(sel, (ln & 48) | (bin >> 3));
                if (sub == 0) accs += hsel - (m + __logf(s)) + LOG128;
            }
        }
    }

    // ---- poisson for this gene: thread t < B handles cell t ----
    if (t < B) {
        const float4* la = (const float4*)(latent + (size_t)t * LDIM);
        const float4* rw = (const float4*)(rho_weight + (size_t)gene * LDIM);
        float d = 0.f;
        #pragma unroll
        for (int k = 0; k < LDIM / 4; ++k) {
            float4 a = la[k], w = rw[k];
            d += a.x * w.x + a.y * w.y + a.z * w.z + a.w * w.w;
        }
        float rb = rho_bias[gene];
        float lib = (float)libsize[cells_oi[t]];
        float lrate = __logf(rb) + d + __logf(lib);
        float rate = __expf(lrate);
        unsigned int c = countsT[(size_t)g * B + t];
        float lgam = 0.f;
        for (unsigned int k = 2; k <= c; ++k) lgam += __logf((float)k);
        accs += (float)c * lrate - rate - lgam;
    }

    // ---- block reduce -> single atomic ----
    #pragma unroll
    for (int o = 32; o; o >>= 1) accs += __shfl_xor(accs, o);
    __syncthreads();
    float* red = (float*)blds;
    if (ln == 0) red[wv] = accs;
    __syncthreads();
    if (t == 0) {
        float s = red[0] + red[1] + red[2] + red[3] + red[4] + red[5] + red[6] + red[7];
        atomicAdd(out, -s);
    }
}

extern "C" void kernel_launch(void* const* d_in, const int* in_sizes, int n_in,
                              void* d_out, int out_size, void* d_ws, size_t ws_size,
                              hipStream_t stream) {
    const float* latent         = (const float*)d_in[0];
    const int*   genes_oi       = (const int*)d_in[1];
    const int*   cells_oi       = (const int*)d_in[2];
    const float* cut_coord      = (const float*)d_in[3];
    const int*   cut_pair       = (const int*)d_in[4];
    const int*   cut_gene       = (const int*)d_in[5];
    const int*   local_cxg      = (const int*)d_in[6];
    const float* logit_weight   = (const float*)d_in[7];
    const float* rho_weight     = (const float*)d_in[8];
    const float* rho_bias       = (const float*)d_in[9];
    const int*   libsize        = (const int*)d_in[10];
    const float* spline_heights = (const float*)d_in[11];
    int G = in_sizes[1];
    int B = in_sizes[2];
    int ncuts = in_sizes[4];
    int nheights = in_sizes[11];
    int nlat = B * LDIM;
    unsigned int magicG = (unsigned int)((0x100000000ULL + (unsigned)G - 1) / (unsigned)G);

    // workspace layout (256-B aligned); zeroed prefix = countsT + cnt_rep
    char* ws = (char*)d_ws;
    size_t off = 0;
    unsigned int* countsT = (unsigned int*)(ws + off);
    off += ((size_t)B * G * 4 + 255) & ~(size_t)255;
    unsigned int* cnt_rep = (unsigned int*)(ws + off);
    off += ((size_t)G * NREP * 4 + 255) & ~(size_t)255;
    size_t zero_bytes = off;
    unsigned int* bucket = (unsigned int*)(ws + off);
    off += ((size_t)G * MAXPER * 4 + 255) & ~(size_t)255;
    unsigned short* hbf = (unsigned short*)(ws + off);
    off += ((size_t)nheights * 2 + 255) & ~(size_t)255;
    unsigned short* latbf = (unsigned short*)(ws + off);
    off += ((size_t)nlat * 2 + 255) & ~(size_t)255;

    float* out = (float*)d_out;
    zero_kernel<<<1024, 256, 0, stream>>>((uint4*)ws, zero_bytes / 16, out, out_size);

    int N = ncuts > nheights ? ncuts : nheights;
    prep1_kernel<<<2048, 256, 0, stream>>>(
        spline_heights, hbf, nheights, latent, latbf, nlat,
        cut_pair, cut_gene, cut_coord, genes_oi, local_cxg,
        cnt_rep, bucket, countsT, ncuts, B, G, N, magicG);
    fused_kernel<<<G, 512, 0, stream>>>(
        latent, latbf, genes_oi, logit_weight, hbf, bucket,
        cnt_rep, countsT, cells_oi,
        rho_weight, rho_bias, libsize, B, G, out);
}